// Round 11
// baseline (496.792 us; speedup 1.0000x reference)
//
#include <hip/hip_runtime.h>
#include <math.h>

#define BATCH 32
#define CH 768
#define HW 3136           // 56*56
#define HW4 (HW/4)        // 784 float4 per plane = 3*256 + 16
#define HID 48
#define PLANES (BATCH*CH) // 24576
#define NBLK 1024         // 4 blocks/CU -> entire grid co-resident (launch_bounds(256,4))
#define BPI 32            // blocks per image
#define PPB 24            // planes per block (768/32)
#define PPW 6             // planes per wave (24/4)
#define CNT_STRIDE 32     // ints; pad counters to 128B to avoid polling contention

typedef float nfloat4 __attribute__((ext_vector_type(4)));

__global__ __launch_bounds__(256, 4) void cbam_onepass(
    const float* __restrict__ x,
    const float* __restrict__ w1,   // [HID, CH]
    const float* __restrict__ w2,   // [CH, HID]
    float* __restrict__ out,
    float* __restrict__ avg,
    float* __restrict__ mx,
    int* __restrict__ cnt)          // BATCH counters, stride CNT_STRIDE, pre-zeroed
{
    const int g    = blockIdx.x;
    const int img  = g >> 5;        // g / BPI
    const int sub  = g & 31;        // g % BPI
    const int wave = threadIdx.x >> 6;
    const int lane = threadIdx.x & 63;

    __shared__ float sa[CH];
    __shared__ float sv[CH];
    __shared__ float ha[HID];
    __shared__ float hm[HID];
    __shared__ float hsum[HID];
    __shared__ float sgate[PPB];

    // ---------- Phase 1: pool own 24 planes (strided by 32 -> sliding window per image) ----------
    for (int pi = 0; pi < PPW; ++pi) {
        const int k = wave * PPW + pi;                 // 0..23
        const int plane = img * CH + sub + BPI * k;
        const nfloat4* xp = reinterpret_cast<const nfloat4*>(x + (size_t)plane * HW);
        float s = 0.0f;
        float m = -INFINITY;
        #pragma unroll
        for (int j = 0; j < 3; ++j) {
            const int base = j * 256 + lane;
            nfloat4 a = xp[base];
            nfloat4 b = xp[base + 64];
            nfloat4 c = xp[base + 128];
            nfloat4 d = xp[base + 192];
            s += ((a.x + a.y) + (a.z + a.w)) + ((b.x + b.y) + (b.z + b.w))
               + ((c.x + c.y) + (c.z + c.w)) + ((d.x + d.y) + (d.z + d.w));
            float ma = fmaxf(fmaxf(a.x, a.y), fmaxf(a.z, a.w));
            float mb = fmaxf(fmaxf(b.x, b.y), fmaxf(b.z, b.w));
            float mc = fmaxf(fmaxf(c.x, c.y), fmaxf(c.z, c.w));
            float md = fmaxf(fmaxf(d.x, d.y), fmaxf(d.z, d.w));
            m = fmaxf(m, fmaxf(fmaxf(ma, mb), fmaxf(mc, md)));
        }
        if (lane < 16) {
            nfloat4 a = xp[768 + lane];
            s += (a.x + a.y) + (a.z + a.w);
            m = fmaxf(m, fmaxf(fmaxf(a.x, a.y), fmaxf(a.z, a.w)));
        }
        for (int off = 32; off > 0; off >>= 1) {
            s += __shfl_down(s, off, 64);
            m = fmaxf(m, __shfl_down(m, off, 64));
        }
        if (lane == 0) {
            avg[plane] = s * (1.0f / (float)HW);
            mx[plane]  = m;
        }
    }

    // ---------- Image-scope barrier: wait for all 32 blocks of this image ----------
    __threadfence();          // every thread: make own avg/mx stores agent-visible
    __syncthreads();
    if (threadIdx.x == 0) {
        __hip_atomic_fetch_add(&cnt[img * CNT_STRIDE], 1,
                               __ATOMIC_ACQ_REL, __HIP_MEMORY_SCOPE_AGENT);
        while (__hip_atomic_load(&cnt[img * CNT_STRIDE],
                                 __ATOMIC_ACQUIRE, __HIP_MEMORY_SCOPE_AGENT) < BPI) {
            __builtin_amdgcn_s_sleep(8);
        }
    }
    __syncthreads();
    __threadfence();          // acquire for all threads before reading other blocks' avg/mx

    // ---------- Phase 2: redundant per-block MLP for this image ----------
    for (int i = threadIdx.x; i < CH; i += 256) {
        sa[i] = avg[img * CH + i];
        sv[i] = mx[img * CH + i];
    }
    __syncthreads();

    if (threadIdx.x < 2 * HID) {
        const bool is_avg = threadIdx.x < HID;
        const int h = is_avg ? threadIdx.x : threadIdx.x - HID;
        const float4* in4 = reinterpret_cast<const float4*>(is_avg ? sa : sv);
        const float4* wr4 = reinterpret_cast<const float4*>(w1 + (size_t)h * CH);
        float acc = 0.0f;
        #pragma unroll 8
        for (int kk = 0; kk < CH / 4; ++kk) {
            float4 a = in4[kk];
            float4 w = wr4[kk];
            acc += a.x * w.x + a.y * w.y + a.z * w.z + a.w * w.w;
        }
        float gg = 0.5f * acc * (1.0f + erff(acc * 0.70710678118654752f));
        if (is_avg) ha[h] = gg; else hm[h] = gg;
    }
    __syncthreads();
    if (threadIdx.x < HID) hsum[threadIdx.x] = ha[threadIdx.x] + hm[threadIdx.x];
    __syncthreads();

    if (threadIdx.x < PPB) {                       // 24 gates this block needs
        const int c = sub + BPI * threadIdx.x;
        const float4* wr4 = reinterpret_cast<const float4*>(w2 + (size_t)c * HID);
        const float4* hs4 = reinterpret_cast<const float4*>(hsum);
        float acc = 0.0f;
        #pragma unroll
        for (int h = 0; h < HID / 4; ++h) {
            float4 a = hs4[h];
            float4 w = wr4[h];
            acc += a.x * w.x + a.y * w.y + a.z * w.z + a.w * w.w;
        }
        sgate[threadIdx.x] = 1.0f / (1.0f + expf(-acc));
    }
    __syncthreads();

    // ---------- Phase 3: scale own planes (image is L3-hot), nt stores ----------
    for (int pi = 0; pi < PPW; ++pi) {
        const int k = wave * PPW + pi;
        const int plane = img * CH + sub + BPI * k;
        const float gfac = sgate[k];
        const nfloat4* xp = reinterpret_cast<const nfloat4*>(x + (size_t)plane * HW);
        nfloat4* op = reinterpret_cast<nfloat4*>(out + (size_t)plane * HW);
        #pragma unroll
        for (int j = 0; j < 3; ++j) {
            const int base = j * 256 + lane;
            nfloat4 a = xp[base];
            nfloat4 b = xp[base + 64];
            nfloat4 c = xp[base + 128];
            nfloat4 d = xp[base + 192];
            a.x *= gfac; a.y *= gfac; a.z *= gfac; a.w *= gfac;
            b.x *= gfac; b.y *= gfac; b.z *= gfac; b.w *= gfac;
            c.x *= gfac; c.y *= gfac; c.z *= gfac; c.w *= gfac;
            d.x *= gfac; d.y *= gfac; d.z *= gfac; d.w *= gfac;
            __builtin_nontemporal_store(a, &op[base]);
            __builtin_nontemporal_store(b, &op[base + 64]);
            __builtin_nontemporal_store(c, &op[base + 128]);
            __builtin_nontemporal_store(d, &op[base + 192]);
        }
        if (lane < 16) {
            const int i = 768 + lane;
            nfloat4 a = xp[i];
            a.x *= gfac; a.y *= gfac; a.z *= gfac; a.w *= gfac;
            __builtin_nontemporal_store(a, &op[i]);
        }
    }
}

extern "C" void kernel_launch(void* const* d_in, const int* in_sizes, int n_in,
                              void* d_out, int out_size, void* d_ws, size_t ws_size,
                              hipStream_t stream) {
    const float* x  = (const float*)d_in[0];
    const float* w1 = (const float*)d_in[1];
    const float* w2 = (const float*)d_in[2];
    float* out = (float*)d_out;

    float* avg = (float*)d_ws;                  // PLANES floats
    float* mx  = avg + PLANES;                  // PLANES floats
    int*   cnt = (int*)(mx + PLANES);           // BATCH * CNT_STRIDE ints

    // reset image counters every call (d_ws is poisoned once and never re-poisoned)
    hipMemsetAsync(cnt, 0, BATCH * CNT_STRIDE * sizeof(int), stream);

    cbam_onepass<<<NBLK, 256, 0, stream>>>(x, w1, w2, out, avg, mx, cnt);
}